// Round 5
// baseline (359.918 us; speedup 1.0000x reference)
//
#include <hip/hip_runtime.h>

typedef __bf16 bf16x4 __attribute__((ext_vector_type(4)));
typedef __bf16 bf16x8 __attribute__((ext_vector_type(8)));
typedef float f32x4 __attribute__((ext_vector_type(4)));

__device__ __forceinline__ f32x4 mfma16(bf16x8 a, bf16x8 b, f32x4 c) {
    return __builtin_amdgcn_mfma_f32_16x16x32_bf16(a, b, c, 0, 0, 0);
}

// Fused 3-layer MLP: out = relu(relu(x@W0^T+b0)@W1^T+b1)@W2^T + b2
// x:[N,64] f32 -> out:[N,32] f32. bf16 MFMA, fp32 accum.
// Swapped-operand MFMA (D = W·X^T): lane (lr,lg) holds H[ch=16t+4lg+r][node=lr].
// Occupancy build: 1024-thread blocks, NO weight hoisting (all fragments stream
// from LDS in fragment-major conflict-free layout), no reg prefetch.
// Target: VGPR<=64 + LDS 58KB => 2 blocks/CU = 32 waves/CU (100%).
__global__ __launch_bounds__(1024, 8) void cheb_mlp_kernel(
    const float* __restrict__ x,
    const float* __restrict__ W0, const float* __restrict__ b0v,
    const float* __restrict__ W1, const float* __restrict__ b1v,
    const float* __restrict__ W2, const float* __restrict__ b2v,
    float* __restrict__ out, int n_nodes)
{
    // Fragment-major weights: fragment (t,s) of layer L at elem [(Lbase + (t*2+s)*64 + lane)*8].
    // ds_read_b128 at (base + lane*16B) = canonical conflict-free LDS pattern.
    __shared__ __bf16 wfrag[1280 * 8];          // w0:[0,512) w1:[512,1024) w2:[1024,1280) frags
    __shared__ float bias0[64], bias1[64], bias2[32];
    __shared__ __bf16 hbuf[16][16][72];         // per-wave activation staging (padded rows)

    const int tid = threadIdx.x;

    // One-time weight stage: fp32 -> bf16, fragment-major. 1280 fragment-writes.
    for (int f = tid; f < 1280; f += 1024) {
        const float* Wsrc; int fi, base;
        if (f < 512)       { Wsrc = W0; fi = f;        base = 0;    }
        else if (f < 1024) { Wsrc = W1; fi = f - 512;  base = 512;  }
        else               { Wsrc = W2; fi = f - 1024; base = 1024; }
        const int t = fi >> 7, s = (fi >> 6) & 1, l = fi & 63;
        const float* src = Wsrc + (t * 16 + (l & 15)) * 64 + s * 32 + (l >> 4) * 8;
        f32x4 a = *(const f32x4*)src;
        f32x4 b = *(const f32x4*)(src + 4);
        bf16x8 w;
#pragma unroll
        for (int j = 0; j < 4; ++j) { w[j] = (__bf16)a[j]; w[j + 4] = (__bf16)b[j]; }
        *(bf16x8*)&wfrag[(base + fi) * 8] = w;
    }
    if (tid < 64)      { bias0[tid] = b0v[tid]; bias1[tid] = b1v[tid]; }
    else if (tid < 96) { bias2[tid - 64] = b2v[tid - 64]; }
    __syncthreads();

    const int wave = tid >> 6;
    const int lane = tid & 63;
    const int lr = lane & 15;   // A-row (W channel) / D-col (node)
    const int lg = lane >> 4;   // k-offset 8*lg; D-row 4*lg + r

    const int wave_base = blockIdx.x * 1024 + wave * 64;
    if (wave_base >= n_nodes) return;            // after barrier; no more syncs
    const int rem = (n_nodes - wave_base) >> 4;  // N%16==0: whole tiles only
    const int nt = rem < 4 ? rem : 4;

    const float* xbase = x + (size_t)(wave_base + lr) * 64 + lg * 8;
    const __bf16* w0f = &wfrag[lane * 8];        // + (t*2+s)*512 elems per fragment
    const __bf16* w1f = &wfrag[4096 + lane * 8];
    const __bf16* w2f = &wfrag[8192 + lane * 8];

    for (int mt = 0; mt < nt; ++mt) {
        const int m_cur = wave_base + mt * 16;

        // Load current tile (coalesced: wave covers contiguous 4KB) and convert.
        const float* xp = xbase + (size_t)mt * 1024;
        f32x4 cx0 = *(const f32x4*)(xp);
        f32x4 cx1 = *(const f32x4*)(xp + 4);
        f32x4 cx2 = *(const f32x4*)(xp + 32);
        f32x4 cx3 = *(const f32x4*)(xp + 36);

        bf16x8 ax0, ax1;
#pragma unroll
        for (int j = 0; j < 4; ++j) {
            ax0[j]     = (__bf16)cx0[j];
            ax0[j + 4] = (__bf16)cx1[j];
            ax1[j]     = (__bf16)cx2[j];
            ax1[j + 4] = (__bf16)cx3[j];
        }

        // ---- layer 0 (weights streamed from LDS, conflict-free) ----
        f32x4 acc[4];
#pragma unroll
        for (int t = 0; t < 4; ++t) {
            acc[t] = *(const f32x4*)&bias0[t * 16 + lg * 4];
            acc[t] = mfma16(*(const bf16x8*)&w0f[(t * 2 + 0) * 512], ax0, acc[t]);
            acc[t] = mfma16(*(const bf16x8*)&w0f[(t * 2 + 1) * 512], ax1, acc[t]);
        }
#pragma unroll
        for (int t = 0; t < 4; ++t) {
            bf16x4 pk;
#pragma unroll
            for (int r = 0; r < 4; ++r) {
                float v = acc[t][r];
                pk[r] = (__bf16)(v > 0.f ? v : 0.f);
            }
            *(bf16x4*)&hbuf[wave][lr][t * 16 + lg * 4] = pk;
        }

        // ---- layer 1 ----
        bf16x8 ah0 = *(const bf16x8*)&hbuf[wave][lr][lg * 8];
        bf16x8 ah1 = *(const bf16x8*)&hbuf[wave][lr][32 + lg * 8];
#pragma unroll
        for (int t = 0; t < 4; ++t) {
            acc[t] = *(const f32x4*)&bias1[t * 16 + lg * 4];
            acc[t] = mfma16(*(const bf16x8*)&w1f[(t * 2 + 0) * 512], ah0, acc[t]);
            acc[t] = mfma16(*(const bf16x8*)&w1f[(t * 2 + 1) * 512], ah1, acc[t]);
        }
#pragma unroll
        for (int t = 0; t < 4; ++t) {
            bf16x4 pk;
#pragma unroll
            for (int r = 0; r < 4; ++r) {
                float v = acc[t][r];
                pk[r] = (__bf16)(v > 0.f ? v : 0.f);
            }
            *(bf16x4*)&hbuf[wave][lr][t * 16 + lg * 4] = pk;
        }

        // ---- layer 2 (no relu): nontemporal dwordx4 stores ----
        bf16x8 ag0 = *(const bf16x8*)&hbuf[wave][lr][lg * 8];
        bf16x8 ag1 = *(const bf16x8*)&hbuf[wave][lr][32 + lg * 8];
#pragma unroll
        for (int t = 0; t < 2; ++t) {
            f32x4 a2 = *(const f32x4*)&bias2[t * 16 + lg * 4];
            a2 = mfma16(*(const bf16x8*)&w2f[(t * 2 + 0) * 512], ag0, a2);
            a2 = mfma16(*(const bf16x8*)&w2f[(t * 2 + 1) * 512], ag1, a2);
            __builtin_nontemporal_store(a2, (f32x4*)&out[(size_t)(m_cur + lr) * 32 + t * 16 + lg * 4]);
        }
    }
}

extern "C" void kernel_launch(void* const* d_in, const int* in_sizes, int n_in,
                              void* d_out, int out_size, void* d_ws, size_t ws_size,
                              hipStream_t stream) {
    const float* x  = (const float*)d_in[0];
    // d_in[1] = edge_index (int64), d_in[2] = edge_weight — dead inputs (ChebConv K=1).
    const float* W0 = (const float*)d_in[3];
    const float* b0 = (const float*)d_in[4];
    const float* W1 = (const float*)d_in[5];
    const float* b1 = (const float*)d_in[6];
    const float* W2 = (const float*)d_in[7];
    const float* b2 = (const float*)d_in[8];
    float* out = (float*)d_out;

    const int n_nodes = in_sizes[0] / 64;            // 1,000,000
    const int grid = (n_nodes + 1023) / 1024;        // 1024 nodes / block
    cheb_mlp_kernel<<<grid, 1024, 0, stream>>>(x, W0, b0, W1, b1, W2, b2, out, n_nodes);
}

// Round 6
// 74.745 us; speedup vs baseline: 4.8153x; 4.8153x over previous
//
#include <hip/hip_runtime.h>

typedef __bf16 bf16x4 __attribute__((ext_vector_type(4)));
typedef __bf16 bf16x8 __attribute__((ext_vector_type(8)));
typedef float f32x4 __attribute__((ext_vector_type(4)));

__device__ __forceinline__ f32x4 mfma16(bf16x8 a, bf16x8 b, f32x4 c) {
    return __builtin_amdgcn_mfma_f32_16x16x32_bf16(a, b, c, 0, 0, 0);
}

// Fused 3-layer MLP: out = relu(relu(x@W0^T+b0)@W1^T+b1)@W2^T + b2
// x:[N,64] f32 -> out:[N,32] f32. bf16 MFMA, fp32 accum.
// Swapped-operand MFMA (D = W·X^T): lane (lr,lg) holds H[ch=16t+4lg+r][node=lr].
// Occupancy build v2: 512-thread blocks, NO weight hoisting (fragment-major LDS,
// conflict-free ds_read_b128 at base+lane*16), no reg prefetch, NO launch-bounds
// forcing (R2/R5 lesson: forcing the allocator spills catastrophically).
// LDS = 39.5 KB -> 4 blocks/CU; if VGPR lands <=64 that's 32 waves/CU.
__global__ __launch_bounds__(512) void cheb_mlp_kernel(
    const float* __restrict__ x,
    const float* __restrict__ W0, const float* __restrict__ b0v,
    const float* __restrict__ W1, const float* __restrict__ b1v,
    const float* __restrict__ W2, const float* __restrict__ b2v,
    float* __restrict__ out, int n_nodes)
{
    // Fragment-major weights: fragment (t,s) of layer L at elems [(Lbase + (t*2+s)*64 + lane)*8].
    __shared__ __bf16 wfrag[1280 * 8];          // w0:[0,512) w1:[512,1024) w2:[1024,1280)
    __shared__ float bias0[64], bias1[64], bias2[32];
    __shared__ __bf16 hbuf[8][16][72];          // per-wave activation staging

    const int tid = threadIdx.x;

    // One-time weight stage: fp32 -> bf16, fragment-major.
    for (int f = tid; f < 1280; f += 512) {
        const float* Wsrc; int fi, base;
        if (f < 512)       { Wsrc = W0; fi = f;        base = 0;    }
        else if (f < 1024) { Wsrc = W1; fi = f - 512;  base = 512;  }
        else               { Wsrc = W2; fi = f - 1024; base = 1024; }
        const int t = fi >> 7, s = (fi >> 6) & 1, l = fi & 63;
        const float* src = Wsrc + (t * 16 + (l & 15)) * 64 + s * 32 + (l >> 4) * 8;
        f32x4 a = *(const f32x4*)src;
        f32x4 b = *(const f32x4*)(src + 4);
        bf16x8 w;
#pragma unroll
        for (int j = 0; j < 4; ++j) { w[j] = (__bf16)a[j]; w[j + 4] = (__bf16)b[j]; }
        *(bf16x8*)&wfrag[(base + fi) * 8] = w;
    }
    if (tid < 64)      { bias0[tid] = b0v[tid]; bias1[tid] = b1v[tid]; }
    else if (tid < 96) { bias2[tid - 64] = b2v[tid - 64]; }
    __syncthreads();

    const int wave = tid >> 6;
    const int lane = tid & 63;
    const int lr = lane & 15;   // A-row (W channel) / D-col (node)
    const int lg = lane >> 4;   // k-offset 8*lg; D-row 4*lg + r

    const int wave_base = blockIdx.x * 512 + wave * 64;
    if (wave_base >= n_nodes) return;            // after barrier; no more syncs
    const int rem = (n_nodes - wave_base) >> 4;  // N%16==0: whole tiles only
    const int nt = rem < 4 ? rem : 4;

    const float* xbase = x + (size_t)(wave_base + lr) * 64 + lg * 8;
    const __bf16* w0f = &wfrag[lane * 8];        // + (t*2+s)*512 elems per fragment
    const __bf16* w1f = &wfrag[4096 + lane * 8];
    const __bf16* w2f = &wfrag[8192 + lane * 8];

    for (int mt = 0; mt < nt; ++mt) {
        const int m_cur = wave_base + mt * 16;

        // Load current tile (wave covers contiguous 4KB) and convert.
        const float* xp = xbase + (size_t)mt * 1024;
        f32x4 cx0 = *(const f32x4*)(xp);
        f32x4 cx1 = *(const f32x4*)(xp + 4);
        f32x4 cx2 = *(const f32x4*)(xp + 32);
        f32x4 cx3 = *(const f32x4*)(xp + 36);

        bf16x8 ax0, ax1;
#pragma unroll
        for (int j = 0; j < 4; ++j) {
            ax0[j]     = (__bf16)cx0[j];
            ax0[j + 4] = (__bf16)cx1[j];
            ax1[j]     = (__bf16)cx2[j];
            ax1[j + 4] = (__bf16)cx3[j];
        }

        // ---- layer 0 (weights streamed from LDS, conflict-free) ----
        f32x4 acc[4];
#pragma unroll
        for (int t = 0; t < 4; ++t) {
            acc[t] = *(const f32x4*)&bias0[t * 16 + lg * 4];
            acc[t] = mfma16(*(const bf16x8*)&w0f[(t * 2 + 0) * 512], ax0, acc[t]);
            acc[t] = mfma16(*(const bf16x8*)&w0f[(t * 2 + 1) * 512], ax1, acc[t]);
        }
#pragma unroll
        for (int t = 0; t < 4; ++t) {
            bf16x4 pk;
#pragma unroll
            for (int r = 0; r < 4; ++r) {
                float v = acc[t][r];
                pk[r] = (__bf16)(v > 0.f ? v : 0.f);
            }
            *(bf16x4*)&hbuf[wave][lr][t * 16 + lg * 4] = pk;
        }

        // ---- layer 1 ----
        bf16x8 ah0 = *(const bf16x8*)&hbuf[wave][lr][lg * 8];
        bf16x8 ah1 = *(const bf16x8*)&hbuf[wave][lr][32 + lg * 8];
#pragma unroll
        for (int t = 0; t < 4; ++t) {
            acc[t] = *(const f32x4*)&bias1[t * 16 + lg * 4];
            acc[t] = mfma16(*(const bf16x8*)&w1f[(t * 2 + 0) * 512], ah0, acc[t]);
            acc[t] = mfma16(*(const bf16x8*)&w1f[(t * 2 + 1) * 512], ah1, acc[t]);
        }
#pragma unroll
        for (int t = 0; t < 4; ++t) {
            bf16x4 pk;
#pragma unroll
            for (int r = 0; r < 4; ++r) {
                float v = acc[t][r];
                pk[r] = (__bf16)(v > 0.f ? v : 0.f);
            }
            *(bf16x4*)&hbuf[wave][lr][t * 16 + lg * 4] = pk;
        }

        // ---- layer 2 (no relu): nontemporal dwordx4 stores ----
        bf16x8 ag0 = *(const bf16x8*)&hbuf[wave][lr][lg * 8];
        bf16x8 ag1 = *(const bf16x8*)&hbuf[wave][lr][32 + lg * 8];
#pragma unroll
        for (int t = 0; t < 2; ++t) {
            f32x4 a2 = *(const f32x4*)&bias2[t * 16 + lg * 4];
            a2 = mfma16(*(const bf16x8*)&w2f[(t * 2 + 0) * 512], ag0, a2);
            a2 = mfma16(*(const bf16x8*)&w2f[(t * 2 + 1) * 512], ag1, a2);
            __builtin_nontemporal_store(a2, (f32x4*)&out[(size_t)(m_cur + lr) * 32 + t * 16 + lg * 4]);
        }
    }
}

extern "C" void kernel_launch(void* const* d_in, const int* in_sizes, int n_in,
                              void* d_out, int out_size, void* d_ws, size_t ws_size,
                              hipStream_t stream) {
    const float* x  = (const float*)d_in[0];
    // d_in[1] = edge_index (int64), d_in[2] = edge_weight — dead inputs (ChebConv K=1).
    const float* W0 = (const float*)d_in[3];
    const float* b0 = (const float*)d_in[4];
    const float* W1 = (const float*)d_in[5];
    const float* b1 = (const float*)d_in[6];
    const float* W2 = (const float*)d_in[7];
    const float* b2 = (const float*)d_in[8];
    float* out = (float*)d_out;

    const int n_nodes = in_sizes[0] / 64;           // 1,000,000
    const int grid = (n_nodes + 511) / 512;         // 512 nodes / block
    cheb_mlp_kernel<<<grid, 512, 0, stream>>>(x, W0, b0, W1, b1, W2, b2, out, n_nodes);
}